// Round 2
// baseline (364.709 us; speedup 1.0000x reference)
//
#include <hip/hip_runtime.h>

#define T      1024
#define DFEAT  80
#define BT     320     // block threads = 5 waves; 320 = 80*4 = 20*16
#define STILE  4       // s-values per block
#define NW     (BT/64)

// ---------------------------------------------------------------------------
// Kernel 1: centers c[b,t] = d[b,t]/2 + cs[b,t], cumsum in f64 for stability.
// cs = roll(cumsum(d,axis=1),1,axis=1); cs[batch 0, :] = 0 (ref quirk!).
// ---------------------------------------------------------------------------
__global__ void centers_kernel(const float* __restrict__ d, float* __restrict__ c) {
    __shared__ double s[T];
    int b = blockIdx.x;
    int t = threadIdx.x;      // blockDim.x == 1024
    float dv = d[b * T + t];
    s[t] = (double)dv;
    __syncthreads();
    // Hillis-Steele inclusive scan in f64 (association error ~1e-13, irrelevant)
    for (int off = 1; off < T; off <<= 1) {
        double add = (t >= off) ? s[t - off] : 0.0;
        __syncthreads();
        s[t] += add;
        __syncthreads();
    }
    double cs;
    if (b == 0)      cs = 0.0;              // ref zeroes whole first batch row
    else if (t == 0) cs = s[T - 1];         // roll: row total wraps to t=0
    else             cs = s[t - 1];
    c[b * T + t] = (float)((double)dv * 0.5 + cs);
}

// ---------------------------------------------------------------------------
// Kernel 2: per block: one batch b, STILE consecutive s values.
// Phase 1: scores + max-reduce. Phase 2: exp + sum-reduce, e -> LDS.
// Phase 3: u[b,s,:] = sum_t e[t] * h[b,t,:] / sum   (float4 over DFEAT)
// ---------------------------------------------------------------------------
__global__ __launch_bounds__(BT) void align_kernel(
    const float* __restrict__ h, const float* __restrict__ c,
    const float* __restrict__ sigma, float* __restrict__ u, int size)
{
    // e padded: index t + (t>>6) so the 16 t-groups (stride 64) hit distinct banks
    __shared__ float e[STILE][T + 16];
    __shared__ float red[STILE][NW];
    __shared__ float part[16][20][4];   // [t-group][k4][component]

    const int s0   = blockIdx.x * STILE;
    const int b    = blockIdx.y;
    const int tid  = threadIdx.x;
    const int lane = tid & 63, wid = tid >> 6;

    const float sg  = sigma[0];
    const float tss = 2.0f * sg * sg;
    const float* crow = c + b * T;

    // ---- phase 1: scores (mimic ref op order) + per-s max ----
    float sc[STILE][4];
    float mloc[STILE];
    #pragma unroll
    for (int j = 0; j < STILE; j++) mloc[j] = -3.0e38f;
    #pragma unroll
    for (int i = 0; i < 4; i++) {
        int t = tid + i * BT;
        float cv = (t < T) ? crow[t] : 0.0f;
        #pragma unroll
        for (int j = 0; j < STILE; j++) {
            float ts   = (float)(s0 + j) + 1.5f;
            float diff = ts - cv;
            float v    = (t < T) ? (-(diff * diff) / tss) : -3.0e38f;
            sc[j][i] = v;
            mloc[j]  = fmaxf(mloc[j], v);
        }
    }
    #pragma unroll
    for (int o = 32; o > 0; o >>= 1)
        #pragma unroll
        for (int j = 0; j < STILE; j++)
            mloc[j] = fmaxf(mloc[j], __shfl_down(mloc[j], o));
    if (lane == 0)
        #pragma unroll
        for (int j = 0; j < STILE; j++) red[j][wid] = mloc[j];
    __syncthreads();
    float mb[STILE];
    #pragma unroll
    for (int j = 0; j < STILE; j++) {
        float mm = red[j][0];
        for (int w = 1; w < NW; w++) mm = fmaxf(mm, red[j][w]);
        mb[j] = mm;
    }

    // ---- phase 2: exp, store to LDS, per-s sum ----
    float lsum[STILE] = {0.f, 0.f, 0.f, 0.f};
    #pragma unroll
    for (int i = 0; i < 4; i++) {
        int t = tid + i * BT;
        if (t < T) {
            int ti = t + (t >> 6);
            #pragma unroll
            for (int j = 0; j < STILE; j++) {
                float ev = __expf(sc[j][i] - mb[j]);
                e[j][ti] = ev;
                lsum[j] += ev;
            }
        }
    }
    #pragma unroll
    for (int o = 32; o > 0; o >>= 1)
        #pragma unroll
        for (int j = 0; j < STILE; j++)
            lsum[j] += __shfl_down(lsum[j], o);
    __syncthreads();               // red[] max-reads complete before overwrite
    if (lane == 0)
        #pragma unroll
        for (int j = 0; j < STILE; j++) red[j][wid] = lsum[j];
    __syncthreads();
    float inv[STILE];
    #pragma unroll
    for (int j = 0; j < STILE; j++) {
        float tt = 0.f;
        for (int w = 0; w < NW; w++) tt += red[j][w];
        inv[j] = 1.0f / tt;
    }

    // ---- phase 3: weighted sum over t, float4 across DFEAT ----
    const int k4 = tid % 20;       // which float4 of the 20 in a row
    const int g  = tid / 20;       // which 64-wide t-chunk (0..15)
    const float4* hv = (const float4*)(h + (size_t)b * T * DFEAT);
    float4 acc[STILE];
    #pragma unroll
    for (int j = 0; j < STILE; j++) acc[j] = make_float4(0.f, 0.f, 0.f, 0.f);
    const int tbase = g * 64;
    const int ebase = g * 65;      // padded index of t = g*64
    for (int i = 0; i < 64; i++) {
        float4 hvv = hv[(size_t)(tbase + i) * 20 + k4];
        #pragma unroll
        for (int j = 0; j < STILE; j++) {
            float ev = e[j][ebase + i];
            acc[j].x += ev * hvv.x;
            acc[j].y += ev * hvv.y;
            acc[j].z += ev * hvv.z;
            acc[j].w += ev * hvv.w;
        }
    }

    const size_t ubase = ((size_t)b * size + s0) * DFEAT;
    for (int j = 0; j < STILE; j++) {
        __syncthreads();
        part[g][k4][0] = acc[j].x;
        part[g][k4][1] = acc[j].y;
        part[g][k4][2] = acc[j].z;
        part[g][k4][3] = acc[j].w;
        __syncthreads();
        if (tid < DFEAT) {
            int kk4 = tid >> 2, comp = tid & 3;
            float r = 0.f;
            #pragma unroll
            for (int w = 0; w < 16; w++) r += part[w][kk4][comp];
            u[ubase + (size_t)j * DFEAT + tid] = r * inv[j];
        }
    }
}

extern "C" void kernel_launch(void* const* d_in, const int* in_sizes, int n_in,
                              void* d_out, int out_size, void* d_ws, size_t ws_size,
                              hipStream_t stream) {
    const float* h     = (const float*)d_in[0];
    const float* d     = (const float*)d_in[1];
    const float* sigma = (const float*)d_in[2];
    float* u = (float*)d_out;

    int bs   = in_sizes[1] / T;                 // 16
    int size = out_size / (bs * DFEAT);         // 4096

    float* c = (float*)d_ws;                    // bs*T floats scratch

    hipLaunchKernelGGL(centers_kernel, dim3(bs), dim3(T), 0, stream, d, c);
    hipLaunchKernelGGL(align_kernel, dim3(size / STILE, bs), dim3(BT), 0, stream,
                       h, c, sigma, u, size);
}

// Round 6
// 138.660 us; speedup vs baseline: 2.6302x; 2.6302x over previous
//
#include <hip/hip_runtime.h>

#define T      1024
#define DFEAT  80
#define NF4    20          // DFEAT / 4
#define NF4P   21          // padded LDS row stride in float4 (bank spread)
#define CH     160         // h rows staged per LDS chunk
#define MARGIN 40.0f       // W^2 = d0^2 + MARGIN*sigma^2  -> tail cut at e^-20
#define WIN_S  64          // s per block in win_kernel
#define B0_SB  8           // s per block in b0_kernel (4 waves x 2 s)

// ---------------------------------------------------------------------------
// Kernel 1: centers c[b,t] = d[b,t]/2 + cs[b,t], cumsum in f64 for stability.
// cs = roll(cumsum(d,axis=1),1,axis=1); cs[batch 0, :] = 0 (ref quirk!).
// For b>=1, c[b,1..1023] ascending; c[b,0] = rowsum + d0/2 is the global max.
// ---------------------------------------------------------------------------
__global__ void centers_kernel(const float* __restrict__ d, float* __restrict__ c) {
    __shared__ double s[T];
    int b = blockIdx.x;
    int t = threadIdx.x;      // blockDim.x == 1024
    float dv = d[b * T + t];
    s[t] = (double)dv;
    __syncthreads();
    for (int off = 1; off < T; off <<= 1) {
        double add = (t >= off) ? s[t - off] : 0.0;
        __syncthreads();
        s[t] += add;
        __syncthreads();
    }
    double cs;
    if (b == 0)      cs = 0.0;              // ref zeroes whole first batch row
    else if (t == 0) cs = s[T - 1];         // roll: row total wraps to t=0
    else             cs = s[t - 1];
    c[b * T + t] = (float)((double)dv * 0.5 + cs);
}

// first index j in [1, T) with cl[j] >= x ; returns T if none
__device__ __forceinline__ int lower_bound_c(const float* cl, float x) {
    int base = 1, len = T - 1;
    while (len > 0) {
        int half = len >> 1;
        if (cl[base + half] < x) { base += half + 1; len -= half + 1; }
        else len = half;
    }
    return base;
}

// ---------------------------------------------------------------------------
// Kernel 2 (batches 1..15): windowed softmax-weighted sum.
// Scores computed in REFERENCE f32 op order: v = -(dd*dd)/tss, w = exp(v - v0)
// where v0 is the f32 score of the nearest center (== f32 max by monotonicity
// of fl(x^2)). Product forms regress absmax 0.008 -> 0.21 (round-4 lesson).
// ---------------------------------------------------------------------------
__global__ __launch_bounds__(256) void win_kernel(
    const float* __restrict__ h, const float* __restrict__ c,
    const float* __restrict__ sigma, float* __restrict__ u, int size)
{
    __shared__ float  cl[T];
    __shared__ float4 hs[CH * NF4P];
    __shared__ float  wred[4];

    const int b   = blockIdx.y + 1;
    const int s0  = blockIdx.x * WIN_S;
    const int tid = threadIdx.x;
    const int sq  = tid >> 2;          // 0..63: s offset in block
    const int q   = tid & 3;           // quad lane: feature group
    int s = s0 + sq;
    if (s >= size) s = size - 1;       // safety (duplicate writes identical)

    for (int i = tid; i < T; i += 256) cl[i] = c[b * T + i];
    __syncthreads();

    const float sg  = sigma[0];
    const float tss = 2.0f * sg * sg;
    const float ts  = (float)s + 1.5f;

    // nearest center distance d0 (sorted part + rotated-max t=0)
    int ins = lower_bound_c(cl, ts);
    float d0 = fabsf(ts - cl[0]);
    if (ins < T) d0 = fminf(d0, fabsf(cl[ins] - ts));
    if (ins > 1) d0 = fminf(d0, fabsf(ts - cl[ins - 1]));
    const float v0  = -(d0 * d0) / tss;             // f32 max score, ref rounding
    const float Ws  = sqrtf(fmaf(sg * sg, MARGIN, d0 * d0));
    const int   jlo = lower_bound_c(cl, ts - Ws);
    const int   jhi = lower_bound_c(cl, ts + Ws);   // exclusive

    // block-uniform row range from block-max W
    float wmax = Ws;
    #pragma unroll
    for (int o = 32; o > 0; o >>= 1) wmax = fmaxf(wmax, __shfl_xor(wmax, o));
    if ((tid & 63) == 0) wred[tid >> 6] = wmax;
    __syncthreads();
    wmax = fmaxf(fmaxf(wred[0], wred[1]), fmaxf(wred[2], wred[3]));
    const int rlo = lower_bound_c(cl, (float)s0 + 1.5f - wmax);
    const int rhi = lower_bound_c(cl, (float)(s0 + WIN_S - 1) + 1.5f + wmax);

    float4 acc[5];
    #pragma unroll
    for (int i5 = 0; i5 < 5; ++i5) acc[i5] = make_float4(0.f, 0.f, 0.f, 0.f);
    float lsum = 0.f;

    const float4* hb4 = (const float4*)h + (size_t)b * T * NF4;

    for (int r0 = rlo; r0 < rhi; r0 += CH) {
        const int nr = min(CH, rhi - r0);
        __syncthreads();               // previous chunk fully consumed
        for (int i = tid; i < nr * NF4; i += 256) {
            int row = i / NF4, k = i - row * NF4;
            hs[row * NF4P + k] = hb4[(size_t)(r0 + row) * NF4 + k];
        }
        __syncthreads();
        const int a = max(jlo, r0), e = min(jhi, r0 + nr);
        for (int j = a; j < e; ++j) {
            float dd = ts - cl[j];
            float v  = -(dd * dd) / tss;            // ref op order
            float w  = __expf(v - v0);
            lsum += w;
            const float4* hr = &hs[(j - r0) * NF4P + q];
            #pragma unroll
            for (int i5 = 0; i5 < 5; ++i5) {
                float4 hv = hr[4 * i5];
                acc[i5].x += w * hv.x; acc[i5].y += w * hv.y;
                acc[i5].z += w * hv.z; acc[i5].w += w * hv.w;
            }
        }
    }

    // t = 0 (rotated row-max center) from global (single row, L2-hot)
    {
        float dd = ts - cl[0];
        if (fabsf(dd) <= Ws) {
            float v = -(dd * dd) / tss;
            float w = __expf(v - v0);
            lsum += w;
            const float4* hr = hb4 + q;
            #pragma unroll
            for (int i5 = 0; i5 < 5; ++i5) {
                float4 hv = hr[4 * i5];
                acc[i5].x += w * hv.x; acc[i5].y += w * hv.y;
                acc[i5].z += w * hv.z; acc[i5].w += w * hv.w;
            }
        }
    }

    const float inv = 1.0f / lsum;
    float4* ur = (float4*)(u + ((size_t)b * size + s) * DFEAT) + q;
    #pragma unroll
    for (int i5 = 0; i5 < 5; ++i5) {
        float4 a4 = acc[i5];
        ur[4 * i5] = make_float4(a4.x * inv, a4.y * inv, a4.z * inv, a4.w * inv);
    }
}

// ---------------------------------------------------------------------------
// Kernel 3 (batch 0): centers all in [0,0.5) -> full-T softmax per s.
// Same ref-op-order scores. Block: 4 waves x 2 s; lane = (kg 0..3, jsub 0..15).
// ---------------------------------------------------------------------------
__global__ __launch_bounds__(256) void b0_kernel(
    const float* __restrict__ h, const float* __restrict__ c,
    const float* __restrict__ sigma, float* __restrict__ u, int size)
{
    __shared__ float  cl[T];
    __shared__ float4 hs[CH * NF4P];

    const int tid  = threadIdx.x;
    const int wid  = tid >> 6;
    const int lane = tid & 63;
    const int jsub = lane & 15;
    const int kg   = lane >> 4;              // feature group: k = kg + 4*i
    const int sA   = blockIdx.x * B0_SB + wid * 2;
    const int sB   = sA + 1;

    for (int i = tid; i < T; i += 256) cl[i] = c[i];   // batch-0 row
    __syncthreads();

    const float sg  = sigma[0];
    const float tss = 2.0f * sg * sg;
    const float tsA = (float)sA + 1.5f;
    const float tsB = (float)sB + 1.5f;

    // min distance (-> f32 max score) per s
    float dA = 1e30f, dB = 1e30f;
    for (int jj = lane; jj < T; jj += 64) {
        float cv = cl[jj];
        dA = fminf(dA, fabsf(tsA - cv));
        dB = fminf(dB, fabsf(tsB - cv));
    }
    #pragma unroll
    for (int o = 32; o > 0; o >>= 1) {
        dA = fminf(dA, __shfl_xor(dA, o));
        dB = fminf(dB, __shfl_xor(dB, o));
    }
    const float v0A = -(dA * dA) / tss;
    const float v0B = -(dB * dB) / tss;

    float4 accA[5], accB[5];
    #pragma unroll
    for (int i5 = 0; i5 < 5; ++i5) {
        accA[i5] = make_float4(0.f, 0.f, 0.f, 0.f);
        accB[i5] = make_float4(0.f, 0.f, 0.f, 0.f);
    }
    float lsA = 0.f, lsB = 0.f;
    const float4* hb4 = (const float4*)h;    // batch 0

    for (int r0 = 0; r0 < T; r0 += CH) {
        const int nr = min(CH, T - r0);
        __syncthreads();
        for (int i = tid; i < nr * NF4; i += 256) {
            int row = i / NF4, k = i - row * NF4;
            hs[row * NF4P + k] = hb4[(size_t)(r0 + row) * NF4 + k];
        }
        __syncthreads();
        for (int j = r0 + jsub; j < r0 + nr; j += 16) {
            float cv  = cl[j];
            float ddA = tsA - cv, ddB = tsB - cv;
            float vA  = -(ddA * ddA) / tss;          // ref op order
            float vB  = -(ddB * ddB) / tss;
            float wA  = __expf(vA - v0A);
            float wB  = __expf(vB - v0B);
            lsA += wA; lsB += wB;
            const float4* hr = &hs[(j - r0) * NF4P + kg];
            #pragma unroll
            for (int i5 = 0; i5 < 5; ++i5) {
                float4 hv = hr[4 * i5];
                accA[i5].x += wA * hv.x; accA[i5].y += wA * hv.y;
                accA[i5].z += wA * hv.z; accA[i5].w += wA * hv.w;
                accB[i5].x += wB * hv.x; accB[i5].y += wB * hv.y;
                accB[i5].z += wB * hv.z; accB[i5].w += wB * hv.w;
            }
        }
    }

    // reduce over the 16 jsub lanes (same kg): offsets 8,4,2,1
    #pragma unroll
    for (int o = 8; o > 0; o >>= 1) {
        lsA += __shfl_down(lsA, o);
        lsB += __shfl_down(lsB, o);
        #pragma unroll
        for (int i5 = 0; i5 < 5; ++i5) {
            accA[i5].x += __shfl_down(accA[i5].x, o);
            accA[i5].y += __shfl_down(accA[i5].y, o);
            accA[i5].z += __shfl_down(accA[i5].z, o);
            accA[i5].w += __shfl_down(accA[i5].w, o);
            accB[i5].x += __shfl_down(accB[i5].x, o);
            accB[i5].y += __shfl_down(accB[i5].y, o);
            accB[i5].z += __shfl_down(accB[i5].z, o);
            accB[i5].w += __shfl_down(accB[i5].w, o);
        }
    }

    if (jsub == 0) {
        const float invA = 1.0f / lsA, invB = 1.0f / lsB;
        float4* uA = (float4*)(u + (size_t)sA * DFEAT) + kg;
        float4* uB = (float4*)(u + (size_t)sB * DFEAT) + kg;
        #pragma unroll
        for (int i5 = 0; i5 < 5; ++i5) {
            float4 a4 = accA[i5], b4 = accB[i5];
            uA[4 * i5] = make_float4(a4.x * invA, a4.y * invA, a4.z * invA, a4.w * invA);
            uB[4 * i5] = make_float4(b4.x * invB, b4.y * invB, b4.z * invB, b4.w * invB);
        }
    }
}

extern "C" void kernel_launch(void* const* d_in, const int* in_sizes, int n_in,
                              void* d_out, int out_size, void* d_ws, size_t ws_size,
                              hipStream_t stream) {
    const float* h     = (const float*)d_in[0];
    const float* d     = (const float*)d_in[1];
    const float* sigma = (const float*)d_in[2];
    float* u = (float*)d_out;

    int bs   = in_sizes[1] / T;                 // 16
    int size = out_size / (bs * DFEAT);         // 4096

    float* c = (float*)d_ws;                    // bs*T floats scratch

    hipLaunchKernelGGL(centers_kernel, dim3(bs), dim3(T), 0, stream, d, c);
    if (bs > 1)
        hipLaunchKernelGGL(win_kernel, dim3((size + WIN_S - 1) / WIN_S, bs - 1),
                           dim3(256), 0, stream, h, c, sigma, u, size);
    hipLaunchKernelGGL(b0_kernel, dim3(size / B0_SB), dim3(256), 0, stream,
                       h, c, sigma, u, size);
}

// Round 7
// 138.014 us; speedup vs baseline: 2.6425x; 1.0047x over previous
//
#include <hip/hip_runtime.h>

#define T      1024
#define DFEAT  80
#define NF4    20          // DFEAT / 4
#define NF4P   21          // padded LDS row stride in float4 (win_kernel)
#define W_CH   96          // h rows staged per LDS chunk (win_kernel)
#define MARGIN 40.0f       // W^2 = d0^2 + MARGIN*sigma^2  -> tail cut at e^-20
#define WIN_S  64          // s per block in win_kernel
#define B0_CH  128         // h rows per chunk in b0_kernel
#define B0_ST  133         // b0 LDS row stride in float4 (mod 8 == 5: spreads banks)

// ---------------------------------------------------------------------------
// Kernel 1: centers c[b,t] = d[b,t]/2 + cs[b,t], cumsum in f64.
// cs = roll(cumsum(d,axis=1),1,axis=1); cs[batch 0, :] = 0 (ref quirk).
// One wave per batch; f64 shuffle scan (no barriers).
// ---------------------------------------------------------------------------
__global__ __launch_bounds__(64) void centers_kernel(
    const float* __restrict__ d, float* __restrict__ c)
{
    const int b = blockIdx.x, lane = threadIdx.x;   // 64 threads
    const float4* dr4 = (const float4*)(d + (size_t)b * T) + lane * 4;
    float4 a0 = dr4[0], a1 = dr4[1], a2 = dr4[2], a3 = dr4[3];
    float loc[16] = {a0.x,a0.y,a0.z,a0.w, a1.x,a1.y,a1.z,a1.w,
                     a2.x,a2.y,a2.z,a2.w, a3.x,a3.y,a3.z,a3.w};
    double pre[17];
    pre[0] = 0.0;
    #pragma unroll
    for (int i = 0; i < 16; ++i) pre[i + 1] = pre[i] + (double)loc[i];
    const double lsum = pre[16];
    double x = lsum;                                  // inclusive wave scan
    #pragma unroll
    for (int off = 1; off < 64; off <<= 1) {
        double y = __shfl_up(x, off);
        if (lane >= off) x += y;
    }
    const double exclb = x - lsum;                    // sum over lanes < lane
    const double total = __shfl(x, 63);
    const int t0 = lane * 16;
    #pragma unroll
    for (int i = 0; i < 16; ++i) {
        int t = t0 + i;
        double cs;
        if (b == 0)      cs = 0.0;
        else if (t == 0) cs = total;
        else             cs = exclb + pre[i];
        c[(size_t)b * T + t] = (float)((double)loc[i] * 0.5 + cs);
    }
}

// first index j in [1, T) with cl[j] >= x ; returns T if none
__device__ __forceinline__ int lower_bound_c(const float* cl, float x) {
    int base = 1, len = T - 1;
    while (len > 0) {
        int half = len >> 1;
        if (cl[base + half] < x) { base += half + 1; len -= half + 1; }
        else len = half;
    }
    return base;
}

// ---------------------------------------------------------------------------
// Kernel 2 (batches 1..15): windowed softmax-weighted sum.
// Scores in REFERENCE f32 op order: v = -(dd*dd)/tss, w = exp(v - v0),
// v0 = f32 score of nearest center (== f32 max). (round-4 lesson)
// ---------------------------------------------------------------------------
__global__ __launch_bounds__(256) void win_kernel(
    const float* __restrict__ h, const float* __restrict__ c,
    const float* __restrict__ sigma, float* __restrict__ u, int size)
{
    __shared__ float  cl[T];
    __shared__ float4 hs[W_CH * NF4P];
    __shared__ float  wred[4];

    const int b   = blockIdx.y + 1;
    const int s0  = blockIdx.x * WIN_S;
    const int tid = threadIdx.x;
    const int sq  = tid >> 2;          // 0..63: s offset in block
    const int q   = tid & 3;           // quad lane: feature group
    int s = s0 + sq;
    if (s >= size) s = size - 1;

    for (int i = tid; i < T; i += 256) cl[i] = c[(size_t)b * T + i];
    __syncthreads();

    const float sg  = sigma[0];
    const float tss = 2.0f * sg * sg;
    const float ts  = (float)s + 1.5f;

    int ins = lower_bound_c(cl, ts);
    float d0 = fabsf(ts - cl[0]);
    if (ins < T) d0 = fminf(d0, fabsf(cl[ins] - ts));
    if (ins > 1) d0 = fminf(d0, fabsf(ts - cl[ins - 1]));
    const float v0  = -(d0 * d0) / tss;             // f32 max score, ref rounding
    const float Ws  = sqrtf(fmaf(sg * sg, MARGIN, d0 * d0));
    const int   jlo = lower_bound_c(cl, ts - Ws);
    const int   jhi = lower_bound_c(cl, ts + Ws);   // exclusive

    float wmax = Ws;
    #pragma unroll
    for (int o = 32; o > 0; o >>= 1) wmax = fmaxf(wmax, __shfl_xor(wmax, o));
    if ((tid & 63) == 0) wred[tid >> 6] = wmax;
    __syncthreads();
    wmax = fmaxf(fmaxf(wred[0], wred[1]), fmaxf(wred[2], wred[3]));
    const int rlo = lower_bound_c(cl, (float)s0 + 1.5f - wmax);
    const int rhi = lower_bound_c(cl, (float)(s0 + WIN_S - 1) + 1.5f + wmax);

    float4 acc[5];
    #pragma unroll
    for (int i5 = 0; i5 < 5; ++i5) acc[i5] = make_float4(0.f, 0.f, 0.f, 0.f);
    float lsum = 0.f;

    const float4* hb4 = (const float4*)h + (size_t)b * T * NF4;

    for (int r0 = rlo; r0 < rhi; r0 += W_CH) {
        const int nr = min(W_CH, rhi - r0);
        __syncthreads();
        for (int i = tid; i < nr * NF4; i += 256) {
            int row = i / NF4, k = i - row * NF4;
            hs[row * NF4P + k] = hb4[(size_t)(r0 + row) * NF4 + k];
        }
        __syncthreads();
        const int a = max(jlo, r0), e = min(jhi, r0 + nr);
        for (int j = a; j < e; ++j) {
            float dd = ts - cl[j];
            float v  = -(dd * dd) / tss;            // ref op order
            float w  = __expf(v - v0);
            lsum += w;
            const float4* hr = &hs[(j - r0) * NF4P + q];
            #pragma unroll
            for (int i5 = 0; i5 < 5; ++i5) {
                float4 hv = hr[4 * i5];
                acc[i5].x += w * hv.x; acc[i5].y += w * hv.y;
                acc[i5].z += w * hv.z; acc[i5].w += w * hv.w;
            }
        }
    }

    { // t = 0 (rotated row-max center), single global row (L2-hot)
        float dd = ts - cl[0];
        if (fabsf(dd) <= Ws) {
            float v = -(dd * dd) / tss;
            float w = __expf(v - v0);
            lsum += w;
            const float4* hr = hb4 + q;
            #pragma unroll
            for (int i5 = 0; i5 < 5; ++i5) {
                float4 hv = hr[4 * i5];
                acc[i5].x += w * hv.x; acc[i5].y += w * hv.y;
                acc[i5].z += w * hv.z; acc[i5].w += w * hv.w;
            }
        }
    }

    const float inv = 1.0f / lsum;
    float4* ur = (float4*)(u + ((size_t)b * size + s) * DFEAT) + q;
    #pragma unroll
    for (int i5 = 0; i5 < 5; ++i5) {
        float4 a4 = acc[i5];
        ur[4 * i5] = make_float4(a4.x * inv, a4.y * inv, a4.z * inv, a4.w * inv);
    }
}

// ---------------------------------------------------------------------------
// Kernel 3 (batch 0): full-T softmax per s. 4 waves x 4 s = 16 s per block.
// Lane = (kg 0..3, jsub 0..15). LDS h transposed k-major hsT[k][row], row
// stride B0_ST float4 -> each 16-lane kg-group reads 16 CONTIGUOUS float4s
// (conflict-free); staging writes spread ~2.5-way (B0_ST % 8 == 5).
// ---------------------------------------------------------------------------
__global__ __launch_bounds__(256) void b0_kernel(
    const float* __restrict__ h, const float* __restrict__ c,
    const float* __restrict__ sigma, float* __restrict__ u, int size)
{
    __shared__ float  cl[T];
    __shared__ float4 hsT[NF4 * B0_ST];

    const int tid   = threadIdx.x;
    const int wid   = tid >> 6;
    const int lane  = tid & 63;
    const int kg    = lane >> 4;             // feature group: k = kg + 4*i5
    const int jsub  = lane & 15;
    const int sbase = blockIdx.x * 16 + wid * 4;

    for (int i = tid; i < T; i += 256) cl[i] = c[i];   // batch-0 centers
    __syncthreads();

    const float sg  = sigma[0];
    const float tss = 2.0f * sg * sg;
    float ts[4];
    #pragma unroll
    for (int q = 0; q < 4; ++q) ts[q] = (float)(sbase + q) + 1.5f;

    // per-s min |ts - c|  ->  f32 max score v0 (ref rounding)
    float dm[4] = {1e30f, 1e30f, 1e30f, 1e30f};
    for (int jj = lane; jj < T; jj += 64) {
        float cv = cl[jj];
        #pragma unroll
        for (int q = 0; q < 4; ++q) dm[q] = fminf(dm[q], fabsf(ts[q] - cv));
    }
    #pragma unroll
    for (int o = 32; o > 0; o >>= 1)
        #pragma unroll
        for (int q = 0; q < 4; ++q) dm[q] = fminf(dm[q], __shfl_xor(dm[q], o));
    float v0[4];
    #pragma unroll
    for (int q = 0; q < 4; ++q) v0[q] = -(dm[q] * dm[q]) / tss;

    float4 acc[4][5];
    #pragma unroll
    for (int q = 0; q < 4; ++q)
        #pragma unroll
        for (int i5 = 0; i5 < 5; ++i5) acc[q][i5] = make_float4(0.f, 0.f, 0.f, 0.f);
    float ls[4] = {0.f, 0.f, 0.f, 0.f};

    const float4* hb4 = (const float4*)h;    // batch 0
    for (int r0 = 0; r0 < T; r0 += B0_CH) {
        __syncthreads();                     // previous chunk consumed
        for (int i = tid; i < B0_CH * NF4; i += 256) {
            int row = i / NF4, k = i - row * NF4;
            hsT[k * B0_ST + row] = hb4[(size_t)(r0 + row) * NF4 + k];
        }
        __syncthreads();
        for (int j = jsub; j < B0_CH; j += 16) {
            float cv = cl[r0 + j];
            float w[4];
            #pragma unroll
            for (int q = 0; q < 4; ++q) {
                float dd = ts[q] - cv;
                float v  = -(dd * dd) / tss;         // ref op order
                w[q] = __expf(v - v0[q]);
                ls[q] += w[q];
            }
            #pragma unroll
            for (int i5 = 0; i5 < 5; ++i5) {
                float4 hv = hsT[(kg + 4 * i5) * B0_ST + j];
                #pragma unroll
                for (int q = 0; q < 4; ++q) {
                    acc[q][i5].x += w[q] * hv.x; acc[q][i5].y += w[q] * hv.y;
                    acc[q][i5].z += w[q] * hv.z; acc[q][i5].w += w[q] * hv.w;
                }
            }
        }
    }

    // reduce over the 16 jsub lanes (same kg): offsets 8,4,2,1
    #pragma unroll
    for (int o = 8; o > 0; o >>= 1) {
        #pragma unroll
        for (int q = 0; q < 4; ++q) {
            ls[q] += __shfl_down(ls[q], o);
            #pragma unroll
            for (int i5 = 0; i5 < 5; ++i5) {
                acc[q][i5].x += __shfl_down(acc[q][i5].x, o);
                acc[q][i5].y += __shfl_down(acc[q][i5].y, o);
                acc[q][i5].z += __shfl_down(acc[q][i5].z, o);
                acc[q][i5].w += __shfl_down(acc[q][i5].w, o);
            }
        }
    }

    if (jsub == 0) {
        #pragma unroll
        for (int q = 0; q < 4; ++q) {
            const float inv = 1.0f / ls[q];
            float4* ur = (float4*)(u + (size_t)(sbase + q) * DFEAT) + kg;
            #pragma unroll
            for (int i5 = 0; i5 < 5; ++i5) {
                float4 a4 = acc[q][i5];
                ur[4 * i5] = make_float4(a4.x * inv, a4.y * inv, a4.z * inv, a4.w * inv);
            }
        }
    }
}

extern "C" void kernel_launch(void* const* d_in, const int* in_sizes, int n_in,
                              void* d_out, int out_size, void* d_ws, size_t ws_size,
                              hipStream_t stream) {
    const float* h     = (const float*)d_in[0];
    const float* d     = (const float*)d_in[1];
    const float* sigma = (const float*)d_in[2];
    float* u = (float*)d_out;

    int bs   = in_sizes[1] / T;                 // 16
    int size = out_size / (bs * DFEAT);         // 4096

    float* c = (float*)d_ws;                    // bs*T floats scratch

    hipLaunchKernelGGL(centers_kernel, dim3(bs), dim3(64), 0, stream, d, c);
    if (bs > 1)
        hipLaunchKernelGGL(win_kernel, dim3((size + WIN_S - 1) / WIN_S, bs - 1),
                           dim3(256), 0, stream, h, c, sigma, u, size);
    hipLaunchKernelGGL(b0_kernel, dim3(size / 16), dim3(256), 0, stream,
                       h, c, sigma, u, size);
}